// Round 13
// baseline (1531.357 us; speedup 1.0000x reference)
//
#include <hip/hip_runtime.h>
#include <hip/hip_bf16.h>

// StencilNet round 12: revert mids to R5-exact (verified 44.4us; R6-R11 all
// regressed). New: fuse layer0 INTO layer1 (k_l01): stage raw input planes
// (5.2KB), compute L0 on the 10x34 halo straight into the swizzled sAct
// layout, then run the verified R5 tap loop. Deletes layer0's 67MB write +
// L1's act read + an entire kernel wall.

#define HW   256
#define MASK 255
#define CH   64
#define TX   32
#define TY   16

typedef short bf16x8 __attribute__((ext_vector_type(8)));
typedef float f32x4  __attribute__((ext_vector_type(4)));

__device__ __forceinline__ float bf2f(unsigned short u) {
    return __uint_as_float(((unsigned int)u) << 16);
}
__device__ __forceinline__ unsigned short f2bf(float f) {
    unsigned int x = __float_as_uint(f);
    return (unsigned short)((x + 0x7fffu + ((x >> 16) & 1u)) >> 16);  // RNE
}

// ---- pack mid-layer weights into 16x16x32 B-frag layout (bf16) -------------
__global__ __launch_bounds__(512) void k_pack(
    const float* __restrict__ w1, const float* __restrict__ w2,
    const float* __restrict__ w3, const float* __restrict__ w4,
    unsigned short* __restrict__ dst)
{
    int g = blockIdx.x * 512 + threadIdx.x;
    if (g >= 4 * 4608) return;
    int L = g / 4608, r = g - L * 4608;
    const float* w = (L == 0) ? w1 : (L == 1) ? w2 : (L == 2) ? w3 : w4;
    int q = r >> 8, n = (r >> 6) & 3, l = r & 63;
    int tap = q >> 1, s = q & 1;
    int ci0 = s * 32 + ((l >> 4) << 3);
    int co  = n * 16 + (l & 15);
    unsigned short o8[8];
#pragma unroll
    for (int j = 0; j < 8; j++)
        o8[j] = f2bf(w[(tap * 64 + ci0 + j) * 64 + co]);
    *reinterpret_cast<uint4*>(dst + (size_t)g * 8) = *reinterpret_cast<uint4*>(o8);
}

// ------------- Fused layer0+layer1: 32x8 tile, 3 blocks/CU -------------------
__global__ __launch_bounds__(512, 4) void k_l01(
    const float* __restrict__ Cin, const float* __restrict__ vx,
    const float* __restrict__ vy, const float* __restrict__ w0,
    const float* __restrict__ b0,
    const unsigned short* __restrict__ wp,   // packed B-frags for layer 1
    const float* __restrict__ b1, unsigned short* __restrict__ out)
{
    __shared__ unsigned short sAct[10 * 34 * CH];  // 43520 B (L0 out halo)
    __shared__ float sIn[3 * 12 * 36];             // 5184 B  (input halo)

    const int t    = threadIdx.x;
    const int lane = t & 63;
    const int wid  = t >> 6;
    const int l15  = lane & 15;
    const int l4   = lane >> 4;

    // XCD-chunked swizzle: 2048 blocks = 8 chunks of 256
    const int bid = blockIdx.x;
    const int tid = (bid & 7) * 256 + (bid >> 3);
    const int bz  = tid >> 8;
    const int rr  = tid & 255;              // 32(y) x 8(x) tiles
    const int y0  = (rr >> 3) * 8;
    const int x0  = (rr & 7) * 32;
    const size_t pbase = (size_t)bz * HW * HW;

    // ---- stage raw input halo 12x36 x 3 planes (f32) ----
    for (int g = t; g < 1296; g += 512) {
        int p = g / 432, rem = g - p * 432;
        int r = rem / 36, c = rem - r * 36;
        int gy = (y0 + r - 2) & MASK;
        int gx = (x0 + c - 2) & MASK;
        const float* src = (p == 0) ? Cin : (p == 1) ? vx : vy;
        sIn[g] = src[pbase + (size_t)gy * HW + gx];
    }
    __syncthreads();

    // ---- L0 compute: 340 halo px x 4 co-chunks, direct into swizzled sAct ---
    for (int g = t; g < 1360; g += 512) {
        int hp = g >> 2, c4 = g & 3;
        int hr = hp / 34, hc = hp - hr * 34;
        float a16[16];
#pragma unroll
        for (int j = 0; j < 16; j++) a16[j] = b0[c4 * 16 + j];
#pragma unroll
        for (int k = 0; k < 27; k++) {
            const int tap = k / 3, ci = k - tap * 3;
            const int ky = tap / 3, kx = tap - ky * 3;
            float av = sIn[ci * 432 + (hr + ky) * 36 + (hc + kx)];
            const float* wq = w0 + k * CH + c4 * 16;
#pragma unroll
            for (int j = 0; j < 16; j++) a16[j] = fmaf(av, wq[j], a16[j]);
        }
        unsigned short o16[16];
#pragma unroll
        for (int j = 0; j < 16; j++) o16[j] = f2bf(fmaxf(a16[j], 0.f));
#pragma unroll
        for (int u = 0; u < 2; u++) {
            int oc = c4 * 2 + u;
            *reinterpret_cast<uint4*>(&sAct[hp * 64 + ((oc ^ (hp & 7)) << 3)]) =
                *reinterpret_cast<uint4*>(o16 + u * 8);
        }
    }

    // B-frag prefetch for q=0 (overlaps L0 tail)
    bf16x8 bnx[4];
#pragma unroll
    for (int n = 0; n < 4; n++)
        bnx[n] = *reinterpret_cast<const bf16x8*>(wp + (size_t)(n * 512 + lane * 8));

    __syncthreads();

    // ---- L1 tap loop (R5 structure, 2 M-frags x 4 N-frags) ----
    f32x4 acc[2][4];
#pragma unroll
    for (int m = 0; m < 2; m++)
#pragma unroll
        for (int n = 0; n < 4; n++) {
            float bv = b1[n * 16 + l15];
            acc[m][n] = (f32x4){bv, bv, bv, bv};
        }

    int pxb[2];
#pragma unroll
    for (int m = 0; m < 2; m++)
        pxb[m] = wid * 34 + m * 16 + l15;

#pragma unroll
    for (int tap = 0; tap < 9; tap++) {
        const int koff = (tap / 3) * 34 + (tap % 3);
#pragma unroll
        for (int s = 0; s < 2; s++) {
            const int q = tap * 2 + s;
            bf16x8 bc[4];
#pragma unroll
            for (int n = 0; n < 4; n++) bc[n] = bnx[n];
            if (q < 17) {
#pragma unroll
                for (int n = 0; n < 4; n++)
                    bnx[n] = *reinterpret_cast<const bf16x8*>(
                        wp + (size_t)(((q + 1) * 4 + n) * 512 + lane * 8));
            }
            const int o = s * 4 + l4;
#pragma unroll
            for (int m = 0; m < 2; m++) {
                int px  = pxb[m] + koff;
                int off = (px << 6) + (((o ^ px) & 7) << 3);
                bf16x8 af = *reinterpret_cast<const bf16x8*>(&sAct[off]);
#pragma unroll
                for (int n = 0; n < 4; n++)
                    acc[m][n] = __builtin_amdgcn_mfma_f32_16x16x32_bf16(
                        af, bc[n], acc[m][n], 0, 0, 0);
            }
        }
    }

    // ---- epilogue (verified R5 mapping) ----
#pragma unroll
    for (int m = 0; m < 2; m++) {
        int y = y0 + wid;
        int x = x0 + m * 16;
        unsigned short* pm = out + (pbase + (size_t)y * HW + x) * CH + (l4 << 8) + l15;
#pragma unroll
        for (int n = 0; n < 4; n++)
#pragma unroll
            for (int j = 0; j < 4; j++)
                pm[j * 64 + n * 16] = f2bf(fmaxf(acc[m][n][j], 0.f));
    }
}

// ------------- Mid layers (R5-exact, verified 44.4us) ------------------------
__global__ __launch_bounds__(512, 4) void k_mid(
    const unsigned short* __restrict__ in,
    const unsigned short* __restrict__ wp,
    const float* __restrict__ b, unsigned short* __restrict__ out)
{
    __shared__ unsigned short sAct[18 * 34 * CH];  // 78336 B -> 2 blocks/CU

    const int t    = threadIdx.x;
    const int lane = t & 63;
    const int wid  = t >> 6;
    const int l15  = lane & 15;
    const int l4   = lane >> 4;

    const int bid = blockIdx.x;
    const int tid = (bid & 7) * 128 + (bid >> 3);
    const int bz  = tid >> 7;
    const int rr  = tid & 127;
    const int y0  = (rr >> 3) * 16;
    const int x0  = (rr & 7) * 32;
    const size_t pbase = (size_t)bz * HW * HW;

    for (int g = t; g < 18 * 34 * 8; g += 512) {
        int hp = g >> 3, cg = g & 7;
        int hr = hp / 34, hc = hp - hr * 34;
        int gy = (y0 + hr - 1) & MASK;
        int gx = (x0 + hc - 1) & MASK;
        uint4 v = *reinterpret_cast<const uint4*>(
            in + ((pbase + (size_t)gy * HW + gx) * CH + cg * 8));
        *reinterpret_cast<uint4*>(&sAct[hp * 64 + ((cg ^ (hp & 7)) << 3)]) = v;
    }

    bf16x8 bnx[4];
#pragma unroll
    for (int n = 0; n < 4; n++)
        bnx[n] = *reinterpret_cast<const bf16x8*>(wp + (size_t)(n * 512 + lane * 8));

    __syncthreads();

    f32x4 acc[4][4];
#pragma unroll
    for (int m = 0; m < 4; m++)
#pragma unroll
        for (int n = 0; n < 4; n++) {
            float bv = b[n * 16 + l15];
            acc[m][n] = (f32x4){bv, bv, bv, bv};
        }

    int pxb[4];
#pragma unroll
    for (int m = 0; m < 4; m++)
        pxb[m] = (2 * wid + (m >> 1)) * 34 + (m & 1) * 16 + l15;

#pragma unroll
    for (int tap = 0; tap < 9; tap++) {
        const int koff = (tap / 3) * 34 + (tap % 3);
#pragma unroll
        for (int s = 0; s < 2; s++) {
            const int q = tap * 2 + s;
            bf16x8 bc[4];
#pragma unroll
            for (int n = 0; n < 4; n++) bc[n] = bnx[n];
            if (q < 17) {
#pragma unroll
                for (int n = 0; n < 4; n++)
                    bnx[n] = *reinterpret_cast<const bf16x8*>(
                        wp + (size_t)(((q + 1) * 4 + n) * 512 + lane * 8));
            }
            const int o = s * 4 + l4;
#pragma unroll
            for (int m = 0; m < 4; m++) {
                int px  = pxb[m] + koff;
                int off = (px << 6) + (((o ^ px) & 7) << 3);
                bf16x8 af = *reinterpret_cast<const bf16x8*>(&sAct[off]);
#pragma unroll
                for (int n = 0; n < 4; n++)
                    acc[m][n] = __builtin_amdgcn_mfma_f32_16x16x32_bf16(
                        af, bc[n], acc[m][n], 0, 0, 0);
            }
        }
    }

#pragma unroll
    for (int m = 0; m < 4; m++) {
        int y = y0 + 2 * wid + (m >> 1);
        int x = x0 + (m & 1) * 16;
        unsigned short* pm = out + (pbase + (size_t)y * HW + x) * CH + (l4 << 8) + l15;
#pragma unroll
        for (int n = 0; n < 4; n++)
#pragma unroll
            for (int j = 0; j < 4; j++)
                pm[j * 64 + n * 16] = f2bf(fmaxf(acc[m][n][j], 0.f));
    }
}

// -------- Output layer MFMA: 64ch -> 16 coeffs + fused 4x4 stencil dot -------
__global__ __launch_bounds__(512, 2) void k_out_mfma(
    const unsigned short* __restrict__ in, const float* __restrict__ w,
    const float* __restrict__ b, const float* __restrict__ Cin,
    float* __restrict__ out)
{
    __shared__ unsigned short sAct[18 * 34 * CH];   // 78336 B
    __shared__ unsigned short sW[9 * 128 * 8];      // 18432 B
    __shared__ float sC[19 * 35];                   // 2660 B

    const int t    = threadIdx.x;
    const int lane = t & 63;
    const int wid  = t >> 6;
    const int l15  = lane & 15;
    const int l4   = lane >> 4;
    const int x0   = blockIdx.x * 32;
    const int y0   = blockIdx.y * 16;
    const size_t pbase = (size_t)blockIdx.z * HW * HW;

    for (int g = t; g < 18 * 34 * 8; g += 512) {
        int hp = g >> 3, cg = g & 7;
        int hr = hp / 34, hc = hp - hr * 34;
        int gy = (y0 + hr - 1) & MASK;
        int gx = (x0 + hc - 1) & MASK;
        uint4 v = *reinterpret_cast<const uint4*>(
            in + ((pbase + gy * HW + gx) * CH + cg * 8));
        *reinterpret_cast<uint4*>(&sAct[hp * 64 + ((cg ^ (hp & 7)) << 3)]) = v;
    }
    for (int g = t; g < 1152; g += 512) {
        int tap = g >> 7, s = (g >> 6) & 1, dl = g & 63;
        int ci0 = s * 32 + (dl >> 4) * 8;
        int co  = dl & 15;
        unsigned short o8[8];
#pragma unroll
        for (int j = 0; j < 8; j++)
            o8[j] = f2bf(w[(tap * 64 + ci0 + j) * 16 + co]);
        *reinterpret_cast<uint4*>(&sW[g * 8]) = *reinterpret_cast<uint4*>(o8);
    }
    for (int g = t; g < 19 * 35; g += 512) {
        int r = g / 35, c2 = g - r * 35;
        int gy = (y0 + r - 2) & MASK;
        int gx = (x0 + c2 - 2) & MASK;
        sC[g] = Cin[pbase + gy * HW + gx];
    }
    __syncthreads();

    f32x4 acc[4];
    {
        float bv = b[l15];
#pragma unroll
        for (int m = 0; m < 4; m++) acc[m] = (f32x4){bv, bv, bv, bv};
    }

    int pxb[4];
#pragma unroll
    for (int m = 0; m < 4; m++)
        pxb[m] = (2 * wid + (m >> 1)) * 34 + (m & 1) * 16 + l15;

    for (int tap = 0; tap < 9; tap++) {
        const int koff = (tap / 3) * 34 + (tap % 3);
#pragma unroll
        for (int s = 0; s < 2; s++) {
            bf16x8 bf = *reinterpret_cast<const bf16x8*>(
                &sW[((tap * 2 + s) << 9) + (lane << 3)]);
            const int o = s * 4 + l4;
#pragma unroll
            for (int m = 0; m < 4; m++) {
                int px  = pxb[m] + koff;
                int off = (px << 6) + (((o ^ px) & 7) << 3);
                bf16x8 af = *reinterpret_cast<const bf16x8*>(&sAct[off]);
                acc[m] = __builtin_amdgcn_mfma_f32_16x16x32_bf16(
                    af, bf, acc[m], 0, 0, 0);
            }
        }
    }

#pragma unroll
    for (int m = 0; m < 4; m++) {
        int py = 2 * wid + (m >> 1);
        int xb = (m & 1) * 16 + l4 * 4;
#pragma unroll
        for (int j = 0; j < 4; j++) {
            int xt = xb + j;
            float v = acc[m][j] * sC[(py + (l15 >> 2)) * 35 + xt + (l15 & 3)];
            v += __shfl_xor(v, 1);
            v += __shfl_xor(v, 2);
            v += __shfl_xor(v, 4);
            v += __shfl_xor(v, 8);
            if (l15 == 0)
                out[pbase + (y0 + py) * HW + x0 + xt] = v;
        }
    }
}

extern "C" void kernel_launch(void* const* d_in, const int* in_sizes, int n_in,
                              void* d_out, int out_size, void* d_ws, size_t ws_size,
                              hipStream_t stream)
{
    (void)in_sizes; (void)n_in; (void)out_size; (void)ws_size;
    const float* Cin  = (const float*)d_in[0];
    const float* vx   = (const float*)d_in[1];
    const float* vy   = (const float*)d_in[2];
    const float* w0   = (const float*)d_in[3];
    const float* b0   = (const float*)d_in[4];
    const float* w1   = (const float*)d_in[5];
    const float* b1   = (const float*)d_in[6];
    const float* w2   = (const float*)d_in[7];
    const float* b2   = (const float*)d_in[8];
    const float* w3   = (const float*)d_in[9];
    const float* b3   = (const float*)d_in[10];
    const float* w4   = (const float*)d_in[11];
    const float* b4   = (const float*)d_in[12];
    const float* wout = (const float*)d_in[13];
    const float* bout = (const float*)d_in[14];

    unsigned short* actA = (unsigned short*)d_ws;
    unsigned short* actB = actA + (size_t)8 * HW * HW * CH;

    unsigned short* wpk = (unsigned short*)d_out;   // parked; k_out rewrites

    dim3 block(512);
    dim3 gridL(2048);
    dim3 gridM(1024);
    dim3 gridO(HW / 32, HW / 16, 8);

    k_pack    <<<36, block, 0, stream>>>(w1, w2, w3, w4, wpk);
    k_l01     <<<gridL, block, 0, stream>>>(Cin, vx, vy, w0, b0,
                                            wpk + 0 * 36864, b1, actB);
    k_mid     <<<gridM, block, 0, stream>>>(actB, wpk + 1 * 36864, b2, actA);
    k_mid     <<<gridM, block, 0, stream>>>(actA, wpk + 2 * 36864, b3, actB);
    k_mid     <<<gridM, block, 0, stream>>>(actB, wpk + 3 * 36864, b4, actA);
    k_out_mfma<<<gridO, block, 0, stream>>>(actA, wout, bout, Cin, (float*)d_out);
}

// Round 14
// 294.007 us; speedup vs baseline: 5.2086x; 5.2086x over previous
//
#include <hip/hip_runtime.h>
#include <hip/hip_bf16.h>

// StencilNet round 13: R12 with ONE fix. Root cause of every spill since R5:
// __launch_bounds__(512,4) = min 4 waves/EU = 64-VGPR cap per wave. k_l01's
// L0 phase (a16[16]+o16[16]) blew that cap -> 3.7GB scratch traffic. Fix:
// k_l01 at (512,2) (128-VGPR cap, LDS still allows 3 blocks/CU) and L0 in
// 8-channel chunks (a8[8] live). k_mid stays R5-exact at (512,4) -- it fits
// 64 exactly. k_pack / k_out_mfma unchanged.

#define HW   256
#define MASK 255
#define CH   64
#define TX   32
#define TY   16

typedef short bf16x8 __attribute__((ext_vector_type(8)));
typedef float f32x4  __attribute__((ext_vector_type(4)));

__device__ __forceinline__ float bf2f(unsigned short u) {
    return __uint_as_float(((unsigned int)u) << 16);
}
__device__ __forceinline__ unsigned short f2bf(float f) {
    unsigned int x = __float_as_uint(f);
    return (unsigned short)((x + 0x7fffu + ((x >> 16) & 1u)) >> 16);  // RNE
}

// ---- pack mid-layer weights into 16x16x32 B-frag layout (bf16) -------------
__global__ __launch_bounds__(512) void k_pack(
    const float* __restrict__ w1, const float* __restrict__ w2,
    const float* __restrict__ w3, const float* __restrict__ w4,
    unsigned short* __restrict__ dst)
{
    int g = blockIdx.x * 512 + threadIdx.x;
    if (g >= 4 * 4608) return;
    int L = g / 4608, r = g - L * 4608;
    const float* w = (L == 0) ? w1 : (L == 1) ? w2 : (L == 2) ? w3 : w4;
    int q = r >> 8, n = (r >> 6) & 3, l = r & 63;
    int tap = q >> 1, s = q & 1;
    int ci0 = s * 32 + ((l >> 4) << 3);
    int co  = n * 16 + (l & 15);
    unsigned short o8[8];
#pragma unroll
    for (int j = 0; j < 8; j++)
        o8[j] = f2bf(w[(tap * 64 + ci0 + j) * 64 + co]);
    *reinterpret_cast<uint4*>(dst + (size_t)g * 8) = *reinterpret_cast<uint4*>(o8);
}

// ------------- Fused layer0+layer1: 32x8 tile, (512,2) -----------------------
__global__ __launch_bounds__(512, 2) void k_l01(
    const float* __restrict__ Cin, const float* __restrict__ vx,
    const float* __restrict__ vy, const float* __restrict__ w0,
    const float* __restrict__ b0,
    const unsigned short* __restrict__ wp,   // packed B-frags for layer 1
    const float* __restrict__ b1, unsigned short* __restrict__ out)
{
    __shared__ unsigned short sAct[10 * 34 * CH];  // 43520 B (L0 out halo)
    __shared__ float sIn[3 * 12 * 36];             // 5184 B  (input halo)

    const int t    = threadIdx.x;
    const int lane = t & 63;
    const int wid  = t >> 6;
    const int l15  = lane & 15;
    const int l4   = lane >> 4;

    // XCD-chunked swizzle: 2048 blocks = 8 chunks of 256
    const int bid = blockIdx.x;
    const int tid = (bid & 7) * 256 + (bid >> 3);
    const int bz  = tid >> 8;
    const int rr  = tid & 255;              // 32(y) x 8(x) tiles
    const int y0  = (rr >> 3) * 8;
    const int x0  = (rr & 7) * 32;
    const size_t pbase = (size_t)bz * HW * HW;

    // ---- stage raw input halo 12x36 x 3 planes (f32) ----
    for (int g = t; g < 1296; g += 512) {
        int p = g / 432, rem = g - p * 432;
        int r = rem / 36, c = rem - r * 36;
        int gy = (y0 + r - 2) & MASK;
        int gx = (x0 + c - 2) & MASK;
        const float* src = (p == 0) ? Cin : (p == 1) ? vx : vy;
        sIn[g] = src[pbase + (size_t)gy * HW + gx];
    }
    __syncthreads();

    // ---- L0 compute: 340 halo px x 8 octets, 8 channels live per granule ----
    for (int g = t; g < 2720; g += 512) {
        int hp = g >> 3, oc = g & 7;
        int hr = hp / 34, hc = hp - hr * 34;
        float a8[8];
#pragma unroll
        for (int j = 0; j < 8; j++) a8[j] = b0[oc * 8 + j];
#pragma unroll
        for (int k = 0; k < 27; k++) {
            const int tap = k / 3, ci = k - tap * 3;
            const int ky = tap / 3, kx = tap - ky * 3;
            float av = sIn[ci * 432 + (hr + ky) * 36 + (hc + kx)];
            const float* wq = w0 + k * CH + oc * 8;
#pragma unroll
            for (int j = 0; j < 8; j++) a8[j] = fmaf(av, wq[j], a8[j]);
        }
        unsigned short o8[8];
#pragma unroll
        for (int j = 0; j < 8; j++) o8[j] = f2bf(fmaxf(a8[j], 0.f));
        *reinterpret_cast<uint4*>(&sAct[hp * 64 + ((oc ^ (hp & 7)) << 3)]) =
            *reinterpret_cast<uint4*>(o8);
    }

    // B-frag prefetch for q=0 (overlaps L0 tail)
    bf16x8 bnx[4];
#pragma unroll
    for (int n = 0; n < 4; n++)
        bnx[n] = *reinterpret_cast<const bf16x8*>(wp + (size_t)(n * 512 + lane * 8));

    __syncthreads();

    // ---- L1 tap loop (R5 structure, 2 M-frags x 4 N-frags) ----
    f32x4 acc[2][4];
#pragma unroll
    for (int m = 0; m < 2; m++)
#pragma unroll
        for (int n = 0; n < 4; n++) {
            float bv = b1[n * 16 + l15];
            acc[m][n] = (f32x4){bv, bv, bv, bv};
        }

    int pxb[2];
#pragma unroll
    for (int m = 0; m < 2; m++)
        pxb[m] = wid * 34 + m * 16 + l15;

#pragma unroll
    for (int tap = 0; tap < 9; tap++) {
        const int koff = (tap / 3) * 34 + (tap % 3);
#pragma unroll
        for (int s = 0; s < 2; s++) {
            const int q = tap * 2 + s;
            bf16x8 bc[4];
#pragma unroll
            for (int n = 0; n < 4; n++) bc[n] = bnx[n];
            if (q < 17) {
#pragma unroll
                for (int n = 0; n < 4; n++)
                    bnx[n] = *reinterpret_cast<const bf16x8*>(
                        wp + (size_t)(((q + 1) * 4 + n) * 512 + lane * 8));
            }
            const int o = s * 4 + l4;
#pragma unroll
            for (int m = 0; m < 2; m++) {
                int px  = pxb[m] + koff;
                int off = (px << 6) + (((o ^ px) & 7) << 3);
                bf16x8 af = *reinterpret_cast<const bf16x8*>(&sAct[off]);
#pragma unroll
                for (int n = 0; n < 4; n++)
                    acc[m][n] = __builtin_amdgcn_mfma_f32_16x16x32_bf16(
                        af, bc[n], acc[m][n], 0, 0, 0);
            }
        }
    }

    // ---- epilogue (verified R5 mapping) ----
#pragma unroll
    for (int m = 0; m < 2; m++) {
        int y = y0 + wid;
        int x = x0 + m * 16;
        unsigned short* pm = out + (pbase + (size_t)y * HW + x) * CH + (l4 << 8) + l15;
#pragma unroll
        for (int n = 0; n < 4; n++)
#pragma unroll
            for (int j = 0; j < 4; j++)
                pm[j * 64 + n * 16] = f2bf(fmaxf(acc[m][n][j], 0.f));
    }
}

// ------------- Mid layers (R5-exact, verified 44.4us) ------------------------
__global__ __launch_bounds__(512, 4) void k_mid(
    const unsigned short* __restrict__ in,
    const unsigned short* __restrict__ wp,
    const float* __restrict__ b, unsigned short* __restrict__ out)
{
    __shared__ unsigned short sAct[18 * 34 * CH];  // 78336 B -> 2 blocks/CU

    const int t    = threadIdx.x;
    const int lane = t & 63;
    const int wid  = t >> 6;
    const int l15  = lane & 15;
    const int l4   = lane >> 4;

    const int bid = blockIdx.x;
    const int tid = (bid & 7) * 128 + (bid >> 3);
    const int bz  = tid >> 7;
    const int rr  = tid & 127;
    const int y0  = (rr >> 3) * 16;
    const int x0  = (rr & 7) * 32;
    const size_t pbase = (size_t)bz * HW * HW;

    for (int g = t; g < 18 * 34 * 8; g += 512) {
        int hp = g >> 3, cg = g & 7;
        int hr = hp / 34, hc = hp - hr * 34;
        int gy = (y0 + hr - 1) & MASK;
        int gx = (x0 + hc - 1) & MASK;
        uint4 v = *reinterpret_cast<const uint4*>(
            in + ((pbase + (size_t)gy * HW + gx) * CH + cg * 8));
        *reinterpret_cast<uint4*>(&sAct[hp * 64 + ((cg ^ (hp & 7)) << 3)]) = v;
    }

    bf16x8 bnx[4];
#pragma unroll
    for (int n = 0; n < 4; n++)
        bnx[n] = *reinterpret_cast<const bf16x8*>(wp + (size_t)(n * 512 + lane * 8));

    __syncthreads();

    f32x4 acc[4][4];
#pragma unroll
    for (int m = 0; m < 4; m++)
#pragma unroll
        for (int n = 0; n < 4; n++) {
            float bv = b[n * 16 + l15];
            acc[m][n] = (f32x4){bv, bv, bv, bv};
        }

    int pxb[4];
#pragma unroll
    for (int m = 0; m < 4; m++)
        pxb[m] = (2 * wid + (m >> 1)) * 34 + (m & 1) * 16 + l15;

#pragma unroll
    for (int tap = 0; tap < 9; tap++) {
        const int koff = (tap / 3) * 34 + (tap % 3);
#pragma unroll
        for (int s = 0; s < 2; s++) {
            const int q = tap * 2 + s;
            bf16x8 bc[4];
#pragma unroll
            for (int n = 0; n < 4; n++) bc[n] = bnx[n];
            if (q < 17) {
#pragma unroll
                for (int n = 0; n < 4; n++)
                    bnx[n] = *reinterpret_cast<const bf16x8*>(
                        wp + (size_t)(((q + 1) * 4 + n) * 512 + lane * 8));
            }
            const int o = s * 4 + l4;
#pragma unroll
            for (int m = 0; m < 4; m++) {
                int px  = pxb[m] + koff;
                int off = (px << 6) + (((o ^ px) & 7) << 3);
                bf16x8 af = *reinterpret_cast<const bf16x8*>(&sAct[off]);
#pragma unroll
                for (int n = 0; n < 4; n++)
                    acc[m][n] = __builtin_amdgcn_mfma_f32_16x16x32_bf16(
                        af, bc[n], acc[m][n], 0, 0, 0);
            }
        }
    }

#pragma unroll
    for (int m = 0; m < 4; m++) {
        int y = y0 + 2 * wid + (m >> 1);
        int x = x0 + (m & 1) * 16;
        unsigned short* pm = out + (pbase + (size_t)y * HW + x) * CH + (l4 << 8) + l15;
#pragma unroll
        for (int n = 0; n < 4; n++)
#pragma unroll
            for (int j = 0; j < 4; j++)
                pm[j * 64 + n * 16] = f2bf(fmaxf(acc[m][n][j], 0.f));
    }
}

// -------- Output layer MFMA: 64ch -> 16 coeffs + fused 4x4 stencil dot -------
__global__ __launch_bounds__(512, 2) void k_out_mfma(
    const unsigned short* __restrict__ in, const float* __restrict__ w,
    const float* __restrict__ b, const float* __restrict__ Cin,
    float* __restrict__ out)
{
    __shared__ unsigned short sAct[18 * 34 * CH];   // 78336 B
    __shared__ unsigned short sW[9 * 128 * 8];      // 18432 B
    __shared__ float sC[19 * 35];                   // 2660 B

    const int t    = threadIdx.x;
    const int lane = t & 63;
    const int wid  = t >> 6;
    const int l15  = lane & 15;
    const int l4   = lane >> 4;
    const int x0   = blockIdx.x * 32;
    const int y0   = blockIdx.y * 16;
    const size_t pbase = (size_t)blockIdx.z * HW * HW;

    for (int g = t; g < 18 * 34 * 8; g += 512) {
        int hp = g >> 3, cg = g & 7;
        int hr = hp / 34, hc = hp - hr * 34;
        int gy = (y0 + hr - 1) & MASK;
        int gx = (x0 + hc - 1) & MASK;
        uint4 v = *reinterpret_cast<const uint4*>(
            in + ((pbase + gy * HW + gx) * CH + cg * 8));
        *reinterpret_cast<uint4*>(&sAct[hp * 64 + ((cg ^ (hp & 7)) << 3)]) = v;
    }
    for (int g = t; g < 1152; g += 512) {
        int tap = g >> 7, s = (g >> 6) & 1, dl = g & 63;
        int ci0 = s * 32 + (dl >> 4) * 8;
        int co  = dl & 15;
        unsigned short o8[8];
#pragma unroll
        for (int j = 0; j < 8; j++)
            o8[j] = f2bf(w[(tap * 64 + ci0 + j) * 16 + co]);
        *reinterpret_cast<uint4*>(&sW[g * 8]) = *reinterpret_cast<uint4*>(o8);
    }
    for (int g = t; g < 19 * 35; g += 512) {
        int r = g / 35, c2 = g - r * 35;
        int gy = (y0 + r - 2) & MASK;
        int gx = (x0 + c2 - 2) & MASK;
        sC[g] = Cin[pbase + gy * HW + gx];
    }
    __syncthreads();

    f32x4 acc[4];
    {
        float bv = b[l15];
#pragma unroll
        for (int m = 0; m < 4; m++) acc[m] = (f32x4){bv, bv, bv, bv};
    }

    int pxb[4];
#pragma unroll
    for (int m = 0; m < 4; m++)
        pxb[m] = (2 * wid + (m >> 1)) * 34 + (m & 1) * 16 + l15;

    for (int tap = 0; tap < 9; tap++) {
        const int koff = (tap / 3) * 34 + (tap % 3);
#pragma unroll
        for (int s = 0; s < 2; s++) {
            bf16x8 bf = *reinterpret_cast<const bf16x8*>(
                &sW[((tap * 2 + s) << 9) + (lane << 3)]);
            const int o = s * 4 + l4;
#pragma unroll
            for (int m = 0; m < 4; m++) {
                int px  = pxb[m] + koff;
                int off = (px << 6) + (((o ^ px) & 7) << 3);
                bf16x8 af = *reinterpret_cast<const bf16x8*>(&sAct[off]);
                acc[m] = __builtin_amdgcn_mfma_f32_16x16x32_bf16(
                    af, bf, acc[m], 0, 0, 0);
            }
        }
    }

#pragma unroll
    for (int m = 0; m < 4; m++) {
        int py = 2 * wid + (m >> 1);
        int xb = (m & 1) * 16 + l4 * 4;
#pragma unroll
        for (int j = 0; j < 4; j++) {
            int xt = xb + j;
            float v = acc[m][j] * sC[(py + (l15 >> 2)) * 35 + xt + (l15 & 3)];
            v += __shfl_xor(v, 1);
            v += __shfl_xor(v, 2);
            v += __shfl_xor(v, 4);
            v += __shfl_xor(v, 8);
            if (l15 == 0)
                out[pbase + (y0 + py) * HW + x0 + xt] = v;
        }
    }
}

extern "C" void kernel_launch(void* const* d_in, const int* in_sizes, int n_in,
                              void* d_out, int out_size, void* d_ws, size_t ws_size,
                              hipStream_t stream)
{
    (void)in_sizes; (void)n_in; (void)out_size; (void)ws_size;
    const float* Cin  = (const float*)d_in[0];
    const float* vx   = (const float*)d_in[1];
    const float* vy   = (const float*)d_in[2];
    const float* w0   = (const float*)d_in[3];
    const float* b0   = (const float*)d_in[4];
    const float* w1   = (const float*)d_in[5];
    const float* b1   = (const float*)d_in[6];
    const float* w2   = (const float*)d_in[7];
    const float* b2   = (const float*)d_in[8];
    const float* w3   = (const float*)d_in[9];
    const float* b3   = (const float*)d_in[10];
    const float* w4   = (const float*)d_in[11];
    const float* b4   = (const float*)d_in[12];
    const float* wout = (const float*)d_in[13];
    const float* bout = (const float*)d_in[14];

    unsigned short* actA = (unsigned short*)d_ws;
    unsigned short* actB = actA + (size_t)8 * HW * HW * CH;

    unsigned short* wpk = (unsigned short*)d_out;   // parked; k_out rewrites

    dim3 block(512);
    dim3 gridL(2048);
    dim3 gridM(1024);
    dim3 gridO(HW / 32, HW / 16, 8);

    k_pack    <<<36, block, 0, stream>>>(w1, w2, w3, w4, wpk);
    k_l01     <<<gridL, block, 0, stream>>>(Cin, vx, vy, w0, b0,
                                            wpk + 0 * 36864, b1, actB);
    k_mid     <<<gridM, block, 0, stream>>>(actB, wpk + 1 * 36864, b2, actA);
    k_mid     <<<gridM, block, 0, stream>>>(actA, wpk + 2 * 36864, b3, actB);
    k_mid     <<<gridM, block, 0, stream>>>(actB, wpk + 3 * 36864, b4, actA);
    k_out_mfma<<<gridO, block, 0, stream>>>(actA, wout, bout, Cin, (float*)d_out);
}